// Round 1
// baseline (80.521 us; speedup 1.0000x reference)
//
#include <hip/hip_runtime.h>
#include <math.h>

#define MAP_SIZE 256
#define KV 64
#define K_SIGN 100000.0f
#define CEPS 1e-5f

__global__ __launch_bounds__(256) void cdm_pass1(
    const float* __restrict__ contour,   // (bn, KV, 2)
    float* __restrict__ out,             // (bn, 256, 256) unnormalized prod
    unsigned int* __restrict__ gmax)     // global max accumulator (float bits)
{
    __shared__ float cx[KV], cy[KV];
    const int blocksPerImg = (MAP_SIZE * MAP_SIZE) / 256;  // 256
    const int bn  = blockIdx.x / blocksPerImg;
    const int pix = (blockIdx.x % blocksPerImg) * 256 + threadIdx.x;

    if (threadIdx.x < KV) {
        cx[threadIdx.x] = contour[(bn * KV + threadIdx.x) * 2 + 0];
        cy[threadIdx.x] = contour[(bn * KV + threadIdx.x) * 2 + 1];
    }
    __syncthreads();

    const float mx = (float)(pix >> 8) * (1.0f / MAP_SIZE);
    const float my = (float)(pix & 255) * (1.0f / MAP_SIZE);

    // diff[0], carried around the loop (each diff/norm computed once)
    const float dx0 = cx[0] - mx, dy0 = cy[0] - my;
    float dx = dx0, dy = dy0;
    float nd = sqrtf(dx * dx + dy * dy);

    float mind = 1e30f;
    float sum  = 0.0f;

    #pragma unroll 4
    for (int k = 0; k < KV; ++k) {
        float rx, ry;
        if (k == KV - 1) { rx = dx0; ry = dy0; }
        else             { rx = cx[k + 1] - mx; ry = cy[k + 1] - my; }
        const float nr = sqrtf(rx * rx + ry * ry);

        mind = fminf(mind, nd);

        const float cross = dy * rx - dx * ry;
        const float s     = tanhf(K_SIGN * cross);

        const float dot = dx * rx + dy * ry;
        const float ndc = fmaxf(nd, CEPS);
        const float nrc = fmaxf(nr, CEPS);
        float ca = dot / (ndc * nrc);
        ca = fminf(fmaxf(ca, -1.0f + CEPS), 1.0f - CEPS);
        sum += s * acosf(ca);

        dx = rx; dy = ry; nd = nr;
    }

    const float inv2pi = 0.15915494309189535f;  // 1/(2*pi)
    const float prod = fabsf(sum) * inv2pi * mind;
    out[bn * (MAP_SIZE * MAP_SIZE) + pix] = prod;

    // block max reduction (prod >= 0, so float bits compare as uint)
    float m = prod;
    #pragma unroll
    for (int off = 32; off > 0; off >>= 1)
        m = fmaxf(m, __shfl_xor(m, off));

    __shared__ float wmax[4];
    const int lane = threadIdx.x & 63;
    const int wid  = threadIdx.x >> 6;
    if (lane == 0) wmax[wid] = m;
    __syncthreads();
    if (threadIdx.x == 0) {
        const float bm = fmaxf(fmaxf(wmax[0], wmax[1]), fmaxf(wmax[2], wmax[3]));
        atomicMax(gmax, __float_as_uint(bm));
    }
}

__global__ __launch_bounds__(256) void cdm_pass2(
    float* __restrict__ out, const unsigned int* __restrict__ gmax, int n)
{
    const float maxv = __uint_as_float(*gmax);
    const int i = blockIdx.x * 256 + threadIdx.x;
    if (i < n) out[i] = out[i] / maxv;
}

extern "C" void kernel_launch(void* const* d_in, const int* in_sizes, int n_in,
                              void* d_out, int out_size, void* d_ws, size_t ws_size,
                              hipStream_t stream) {
    const float* contour = (const float*)d_in[0];
    float* out = (float*)d_out;
    unsigned int* gmax = (unsigned int*)d_ws;

    const int bn = in_sizes[0] / (KV * 2);            // 8
    const int npix = bn * MAP_SIZE * MAP_SIZE;        // 524288 == out_size

    // zero the max accumulator (d_ws is poisoned; 0x00000000 == 0.0f)
    hipMemsetAsync(gmax, 0, sizeof(unsigned int), stream);

    const int blocksPerImg = (MAP_SIZE * MAP_SIZE) / 256;
    cdm_pass1<<<bn * blocksPerImg, 256, 0, stream>>>(contour, out, gmax);
    cdm_pass2<<<(npix + 255) / 256, 256, 0, stream>>>(out, gmax, npix);
}

// Round 2
// 43.286 us; speedup vs baseline: 1.8602x; 1.8602x over previous
//
#include <hip/hip_runtime.h>
#include <math.h>

#define MAP_SIZE 256
#define KV 64

// acos approx (Abramowitz & Stegun 4.4.45): |err| <= ~7e-5 rad
__device__ __forceinline__ float fast_acos(float x) {
    float a = __builtin_fabsf(x);
    float p = fmaf(fmaf(fmaf(-0.0187293f, a, 0.0742610f), a, -0.2121144f), a, 1.5707288f);
    float r = __builtin_amdgcn_sqrtf(1.0f - a) * p;
    return x >= 0.0f ? r : 3.14159274f - r;
}

__global__ __launch_bounds__(256) void cdm_pass1(
    const float* __restrict__ contour,   // (bn, KV, 2)
    float* __restrict__ out,             // (bn, 256, 256) unnormalized prod
    unsigned int* __restrict__ gmax)     // global max accumulator (float bits)
{
    __shared__ float2 cv[KV];
    const int blocksPerImg = (MAP_SIZE * MAP_SIZE) / 256;  // 256
    const int bn  = blockIdx.x / blocksPerImg;
    const int pix = (blockIdx.x % blocksPerImg) * 256 + threadIdx.x;

    if (threadIdx.x < KV) {
        cv[threadIdx.x] = ((const float2*)contour)[bn * KV + threadIdx.x];
    }
    __syncthreads();

    const float mx = (float)(pix >> 8) * (1.0f / MAP_SIZE);
    const float my = (float)(pix & 255) * (1.0f / MAP_SIZE);

    // carried: diff_k, its squared norm, and rsqrt of clamped squared norm
    float dx = cv[0].x - mx, dy = cv[0].y - my;
    float dd = fmaf(dx, dx, dy * dy);
    float rsd = __builtin_amdgcn_rsqf(fmaxf(dd, 1e-10f));

    float mindd = dd;
    float sum = 0.0f;

    const float CLO = -1.0f + 1e-5f;
    const float CHI =  1.0f - 1e-5f;
    const float TK  = 288539.0083f;  // 2 * 100000 * log2(e)

    #pragma unroll 8
    for (int k = 0; k < KV; ++k) {
        const float2 c = cv[(k + 1) & (KV - 1)];
        const float rx = c.x - mx;
        const float ry = c.y - my;
        const float rr = fmaf(rx, rx, ry * ry);
        const float rsr = __builtin_amdgcn_rsqf(fmaxf(rr, 1e-10f));

        mindd = fminf(mindd, dd);

        const float cross = fmaf(dy, rx, -dx * ry);
        const float dot   = fmaf(dx, rx, dy * ry);

        float ca = dot * rsd * rsr;
        ca = fminf(fmaxf(ca, CLO), CHI);
        const float ang = fast_acos(ca);

        // tanh(K*cross) = 1 - 2/(exp2(2K*log2e*cross)+1); inf/0-saturating, NaN-free
        const float e = __builtin_amdgcn_exp2f(cross * TK);
        const float s = fmaf(-2.0f, __builtin_amdgcn_rcpf(e + 1.0f), 1.0f);

        sum = fmaf(s, ang, sum);

        dx = rx; dy = ry; dd = rr; rsd = rsr;
    }

    const float inv2pi = 0.15915494309189535f;
    const float prod = __builtin_fabsf(sum) * inv2pi * __builtin_amdgcn_sqrtf(mindd);
    out[bn * (MAP_SIZE * MAP_SIZE) + pix] = prod;

    // block max reduction (prod >= 0 -> float bits compare as uint)
    float m = prod;
    #pragma unroll
    for (int off = 32; off > 0; off >>= 1)
        m = fmaxf(m, __shfl_xor(m, off));

    __shared__ float wmax[4];
    const int lane = threadIdx.x & 63;
    const int wid  = threadIdx.x >> 6;
    if (lane == 0) wmax[wid] = m;
    __syncthreads();
    if (threadIdx.x == 0) {
        const float bm = fmaxf(fmaxf(wmax[0], wmax[1]), fmaxf(wmax[2], wmax[3]));
        atomicMax(gmax, __float_as_uint(bm));
    }
}

__global__ __launch_bounds__(256) void cdm_pass2(
    float4* __restrict__ out, const unsigned int* __restrict__ gmax, int n4)
{
    const float inv = 1.0f / __uint_as_float(*gmax);
    const int i = blockIdx.x * 256 + threadIdx.x;
    if (i < n4) {
        float4 v = out[i];
        v.x *= inv; v.y *= inv; v.z *= inv; v.w *= inv;
        out[i] = v;
    }
}

extern "C" void kernel_launch(void* const* d_in, const int* in_sizes, int n_in,
                              void* d_out, int out_size, void* d_ws, size_t ws_size,
                              hipStream_t stream) {
    const float* contour = (const float*)d_in[0];
    float* out = (float*)d_out;
    unsigned int* gmax = (unsigned int*)d_ws;

    const int bn = in_sizes[0] / (KV * 2);            // 8
    const int npix = bn * MAP_SIZE * MAP_SIZE;        // 524288 == out_size

    hipMemsetAsync(gmax, 0, sizeof(unsigned int), stream);

    const int blocksPerImg = (MAP_SIZE * MAP_SIZE) / 256;
    cdm_pass1<<<bn * blocksPerImg, 256, 0, stream>>>(contour, out, gmax);

    const int n4 = npix / 4;
    cdm_pass2<<<(n4 + 255) / 256, 256, 0, stream>>>((float4*)out, gmax, n4);
}